// Round 1
// baseline (2477.235 us; speedup 1.0000x reference)
//
#include <hip/hip_runtime.h>
#include <hip/hip_bf16.h>
#include <math.h>

// Problem constants
#define BB 8
#define CC 512
#define CI 256
#define TT 8
#define HH 32
#define WW 32
#define NS (TT*HH*WW)              // 8192 spatial positions
#define MS ((TT/2)*(HH/2)*(WW/2))  // 1024 pooled positions
#define O3 (3*CI)                  // 768 concat output channels

// ---------------------------------------------------------------------------
// 1) concat theta/phi/g weights+biases into W3 (768x512), b3 (768)
__global__ void concat_w_kernel(const float* __restrict__ tw, const float* __restrict__ tb,
                                const float* __restrict__ pw, const float* __restrict__ pb,
                                const float* __restrict__ gw, const float* __restrict__ gb,
                                float* __restrict__ W3, float* __restrict__ b3) {
    int i = blockIdx.x * blockDim.x + threadIdx.x;
    int tot = O3 * CC;
    if (i < tot) {
        int o = i / CC, c = i % CC;
        const float* src = (o < CI) ? tw : (o < 2*CI) ? pw : gw;
        W3[i] = src[(o % CI) * CC + c];
    }
    if (i < O3) {
        const float* srcb = (i < CI) ? tb : (i < 2*CI) ? pb : gb;
        b3[i] = srcb[i % CI];
    }
}

// ---------------------------------------------------------------------------
// 2) Tiled fp32 GEMM: C[b][m][n] = sum_k A[m][k]*B[b][.][.] + bias[m]
//    BT=false: B is [b][K][N] (n contiguous).  BT=true: B is [b][N][K].
template<int BM, int BN, int BK, bool BT>
__global__ __launch_bounds__(256) void gemm_bias(
        const float* __restrict__ A, const float* __restrict__ bias,
        const float* __restrict__ Bm, float* __restrict__ Cm,
        int Mdim, int Ndim, int Kdim) {
    __shared__ float As[BK][BM + 4];
    __shared__ float Bs[BK][BN + 4];
    int b = blockIdx.z;
    const float* Bb = Bm + (size_t)b * Kdim * Ndim;
    float* Cb = Cm + (size_t)b * Mdim * Ndim;
    int m0 = blockIdx.y * BM, n0 = blockIdx.x * BN;
    int tid = threadIdx.x;
    int tx = tid % 16, ty = tid / 16;
    float acc[4][4] = {};

    for (int k0 = 0; k0 < Kdim; k0 += BK) {
        // A tile: read k-contiguous (coalesced), store transposed As[k][m]
        #pragma unroll
        for (int l = 0; l < (BM * BK) / 256; ++l) {
            int idx = tid + l * 256;
            int m = idx / BK, k = idx % BK;
            As[k][m] = A[(size_t)(m0 + m) * Kdim + k0 + k];
        }
        if (!BT) {
            #pragma unroll
            for (int l = 0; l < (BK * BN) / 256; ++l) {
                int idx = tid + l * 256;
                int k = idx / BN, n = idx % BN;
                Bs[k][n] = Bb[(size_t)(k0 + k) * Ndim + n0 + n];
            }
        } else {
            #pragma unroll
            for (int l = 0; l < (BK * BN) / 256; ++l) {
                int idx = tid + l * 256;
                int n = idx / BK, k = idx % BK;
                Bs[k][n] = Bb[(size_t)(n0 + n) * Kdim + k0 + k];
            }
        }
        __syncthreads();
        #pragma unroll
        for (int k = 0; k < BK; ++k) {
            float4 a = *(const float4*)&As[k][ty * 4];
            float4 bv = *(const float4*)&Bs[k][tx * 4];
            float av[4] = {a.x, a.y, a.z, a.w};
            float bw[4] = {bv.x, bv.y, bv.z, bv.w};
            #pragma unroll
            for (int i = 0; i < 4; ++i)
                #pragma unroll
                for (int j = 0; j < 4; ++j)
                    acc[i][j] += av[i] * bw[j];
        }
        __syncthreads();
    }
    #pragma unroll
    for (int i = 0; i < 4; ++i) {
        int m = m0 + ty * 4 + i;
        float bvl = bias[m];
        #pragma unroll
        for (int j = 0; j < 4; ++j)
            Cb[(size_t)m * Ndim + n0 + tx * 4 + j] = acc[i][j] + bvl;
    }
}

// ---------------------------------------------------------------------------
// 3) MaxPool 2x2x2 on phi (rows 256..511 of proj) and g (rows 512..767).
//    kp: [b][ci][m] (ci-major),  vt: [b][m][ci] (m-major, transposed)
__global__ void pool_kernel(const float* __restrict__ proj,
                            float* __restrict__ kp, float* __restrict__ vt) {
    int i = blockIdx.x * blockDim.x + threadIdx.x;
    int tot = 2 * BB * CI * MS;
    if (i >= tot) return;
    int which = i / (BB * CI * MS);
    int r = i % (BB * CI * MS);
    int b = r / (CI * MS);
    int o = (r / MS) % CI;
    int m = r % MS;
    int tp = m / 256, hp = (m / 16) % 16, wp = m % 16;
    const float* src = proj + ((size_t)b * O3 + (which ? 2*CI : CI) + o) * NS;
    float mx = -INFINITY;
    #pragma unroll
    for (int dt = 0; dt < 2; ++dt)
        #pragma unroll
        for (int dh = 0; dh < 2; ++dh)
            #pragma unroll
            for (int dw = 0; dw < 2; ++dw) {
                int n = (2*tp + dt) * 1024 + (2*hp + dh) * 32 + (2*wp + dw);
                mx = fmaxf(mx, src[n]);
            }
    if (which == 0) kp[((size_t)b * CI + o) * MS + m] = mx;
    else            vt[((size_t)b * MS + m) * CI + o] = mx;
}

// ---------------------------------------------------------------------------
// 4) Fused attention: per block, 8 query rows; scores->softmax->PV.
//    proj rows 0..255 = theta (layout [ci][n]); y written [b][n][ci].
__global__ __launch_bounds__(256) void attn_kernel(
        const float* __restrict__ proj, const float* __restrict__ kp,
        const float* __restrict__ vt, float* __restrict__ y) {
    const int BQ = 8;
    __shared__ float q[BQ][CI];      // 8 KB
    __shared__ float s[BQ][MS];      // 32 KB
    __shared__ float rowsum[BQ];

    int b = blockIdx.y;
    int n0 = blockIdx.x * BQ;
    int tid = threadIdx.x;
    int lane = tid & 63, wave = tid >> 6;

    const float* theta = proj + (size_t)b * O3 * NS;
    #pragma unroll
    for (int l = 0; l < (BQ * CI) / 256; ++l) {
        int idx = tid + l * 256;
        int ci = idx / BQ, r = idx % BQ;
        q[r][ci] = theta[(size_t)ci * NS + n0 + r];
    }
    __syncthreads();

    // Phase 1: scores. thread handles m = tid + j*256, j=0..3
    const float* kb = kp + (size_t)b * CI * MS;
    float acc[BQ][4] = {};
    for (int ci = 0; ci < CI; ci += 4) {
        float ka[4][4];
        #pragma unroll
        for (int cc = 0; cc < 4; ++cc) {
            const float* kr = kb + (size_t)(ci + cc) * MS + tid;
            #pragma unroll
            for (int j = 0; j < 4; ++j) ka[cc][j] = kr[j * 256];
        }
        #pragma unroll
        for (int r = 0; r < BQ; ++r) {
            float4 qv = *(const float4*)&q[r][ci];
            #pragma unroll
            for (int j = 0; j < 4; ++j)
                acc[r][j] += qv.x * ka[0][j] + qv.y * ka[1][j]
                           + qv.z * ka[2][j] + qv.w * ka[3][j];
        }
    }
    #pragma unroll
    for (int r = 0; r < BQ; ++r)
        #pragma unroll
        for (int j = 0; j < 4; ++j)
            s[r][j * 256 + tid] = acc[r][j];
    __syncthreads();

    // Phase 2: softmax (store unnormalized exp, keep row sums). wave -> 2 rows.
    #pragma unroll
    for (int rr = 0; rr < 2; ++rr) {
        int r = wave * 2 + rr;
        float mx = -INFINITY;
        for (int j = lane; j < MS; j += 64) mx = fmaxf(mx, s[r][j]);
        #pragma unroll
        for (int off = 32; off > 0; off >>= 1) mx = fmaxf(mx, __shfl_down(mx, off));
        mx = __shfl(mx, 0);
        float sm = 0.f;
        for (int j = lane; j < MS; j += 64) {
            float e = __expf(s[r][j] - mx);
            s[r][j] = e;
            sm += e;
        }
        #pragma unroll
        for (int off = 32; off > 0; off >>= 1) sm += __shfl_down(sm, off);
        if (lane == 0) rowsum[r] = sm;
    }
    __syncthreads();

    // Phase 3: y[r][ci=tid] = sum_m p[r][m] * v[m][ci]
    const float* vb = vt + (size_t)b * MS * CI;
    float yacc[BQ] = {};
    for (int m = 0; m < MS; m += 4) {
        float v0 = vb[(size_t)m * CI + tid];
        float v1 = vb[(size_t)(m + 1) * CI + tid];
        float v2 = vb[(size_t)(m + 2) * CI + tid];
        float v3 = vb[(size_t)(m + 3) * CI + tid];
        #pragma unroll
        for (int r = 0; r < BQ; ++r) {
            float4 sv = *(const float4*)&s[r][m];
            yacc[r] += sv.x * v0 + sv.y * v1 + sv.z * v2 + sv.w * v3;
        }
    }
    float* yb = y + (size_t)b * NS * CI;
    #pragma unroll
    for (int r = 0; r < BQ; ++r)
        yb[(size_t)(n0 + r) * CI + tid] = yacc[r] / rowsum[r];
}

// ---------------------------------------------------------------------------
// 5) BN stats: one block per channel. stats[c]=mean, stats[C+c]=rstd
__global__ __launch_bounds__(256) void bn_stats(const float* __restrict__ z,
                                                float* __restrict__ stats) {
    int c = blockIdx.x;
    int tid = threadIdx.x;
    int lane = tid & 63, wave = tid >> 6;
    float sv = 0.f, sq = 0.f;
    for (int i = tid; i < BB * NS; i += 256) {
        int b = i / NS, n = i % NS;
        float v = z[((size_t)b * CC + c) * NS + n];
        sv += v; sq += v * v;
    }
    #pragma unroll
    for (int off = 32; off > 0; off >>= 1) {
        sv += __shfl_down(sv, off);
        sq += __shfl_down(sq, off);
    }
    __shared__ float rs[4], rq[4];
    if (lane == 0) { rs[wave] = sv; rq[wave] = sq; }
    __syncthreads();
    if (tid == 0) {
        float s = rs[0] + rs[1] + rs[2] + rs[3];
        float q = rq[0] + rq[1] + rq[2] + rq[3];
        const float inv = 1.0f / (BB * NS);
        float mean = s * inv;
        float var = q * inv - mean * mean;
        stats[c] = mean;
        stats[CC + c] = rsqrtf(var + 1e-5f);
    }
}

// ---------------------------------------------------------------------------
// 6) Final: out = (z-mean)*rstd*gamma + beta + x (float4 vectorized)
__global__ __launch_bounds__(256) void bn_final(
        const float* __restrict__ z, const float* __restrict__ x,
        const float* __restrict__ stats, const float* __restrict__ gamma,
        const float* __restrict__ beta, float* __restrict__ out) {
    size_t i = ((size_t)blockIdx.x * 256 + threadIdx.x) * 4;
    int c = (int)((i / NS) % CC);
    float rstd = stats[CC + c];
    float g = gamma[c] * rstd;
    float sh = beta[c] - stats[c] * g;
    float4 zv = *(const float4*)(z + i);
    float4 xv = *(const float4*)(x + i);
    float4 o;
    o.x = zv.x * g + sh + xv.x;
    o.y = zv.y * g + sh + xv.y;
    o.z = zv.z * g + sh + xv.z;
    o.w = zv.w * g + sh + xv.w;
    *(float4*)(out + i) = o;
}

// ---------------------------------------------------------------------------
extern "C" void kernel_launch(void* const* d_in, const int* in_sizes, int n_in,
                              void* d_out, int out_size, void* d_ws, size_t ws_size,
                              hipStream_t stream) {
    const float* x       = (const float*)d_in[0];
    const float* theta_w = (const float*)d_in[1];
    const float* theta_b = (const float*)d_in[2];
    const float* phi_w   = (const float*)d_in[3];
    const float* phi_b   = (const float*)d_in[4];
    const float* g_w     = (const float*)d_in[5];
    const float* g_b     = (const float*)d_in[6];
    const float* wz_w    = (const float*)d_in[7];
    const float* wz_b    = (const float*)d_in[8];
    const float* gamma   = (const float*)d_in[9];
    const float* beta    = (const float*)d_in[10];
    float* ws = (float*)d_ws;

    size_t off = 0;
    float* W3 = ws;               off += (size_t)O3 * CC;      // 393216
    float* b3 = ws + off;         off += O3;                   // 393984
    float* proj = ws + off;       off += (size_t)BB * O3 * NS; // +50331648
    float* kp = ws + off;         off += (size_t)BB * CI * MS;
    float* vt = ws + off;         off += (size_t)BB * MS * CI;
    float* y  = ws + off;         off += (size_t)BB * NS * CI;
    float* stats = ws + off;      off += 2 * CC;
    float* z = proj;  // alias: proj dead after attention

    // 1) concat weights
    concat_w_kernel<<<(O3 * CC + 255) / 256, 256, 0, stream>>>(
        theta_w, theta_b, phi_w, phi_b, g_w, g_b, W3, b3);

    // 2) projections: proj[b][768][8192] = W3 @ x + b3
    gemm_bias<64, 64, 16, false><<<dim3(NS / 64, O3 / 64, BB), 256, 0, stream>>>(
        W3, b3, x, proj, O3, NS, CC);

    // 3) maxpool -> kp (ci-major), vt (m-major)
    pool_kernel<<<(2 * BB * CI * MS + 255) / 256, 256, 0, stream>>>(proj, kp, vt);

    // 4) fused attention -> y[b][n][ci]
    attn_kernel<<<dim3(NS / 8, BB), 256, 0, stream>>>(proj, kp, vt, y);

    // 5) z = wz @ y^T + wz_b   (B-transposed GEMM), z aliases proj
    gemm_bias<64, 64, 16, true><<<dim3(NS / 64, CC / 64, BB), 256, 0, stream>>>(
        wz_w, wz_b, y, z, CC, NS, CI);

    // 6) BN stats
    bn_stats<<<CC, 256, 0, stream>>>(z, stats);

    // 7) normalize + residual
    bn_final<<<(size_t)BB * CC * NS / 4 / 256, 256, 0, stream>>>(
        z, x, stats, gamma, beta, (float*)d_out);
}

// Round 3
// 439.395 us; speedup vs baseline: 5.6378x; 5.6378x over previous
//
#include <hip/hip_runtime.h>
#include <math.h>

typedef unsigned short u16;
typedef __attribute__((ext_vector_type(8))) _Float16 half8;
typedef __attribute__((ext_vector_type(4))) float f32x4;

#define NS 8192
#define MS 1024
#define CCH 512
#define CI 256
#define O3 768

// ---- fp16 helpers (bit-level storage as u16) ----
__device__ __forceinline__ float h2f(u16 u) {
    _Float16 h; *(u16*)&h = u; return (float)h;
}
__device__ __forceinline__ u16 f2h(float f) {
    _Float16 h = (_Float16)f; return *(u16*)&h;
}

// async global->LDS 16B
__device__ __forceinline__ void gld16(u16* lds, const u16* g) {
    __builtin_amdgcn_global_load_lds((const __attribute__((address_space(1))) void*)g,
                                     (__attribute__((address_space(3))) void*)lds,
                                     16, 0, 0);
}

// ---------------------------------------------------------------------------
// prep: concat+convert weights to fp16
__global__ void prep_w(const float* __restrict__ tw, const float* __restrict__ tb,
                       const float* __restrict__ pw, const float* __restrict__ pb,
                       const float* __restrict__ gw, const float* __restrict__ gb,
                       const float* __restrict__ wzw,
                       u16* __restrict__ W3b, float* __restrict__ b3, u16* __restrict__ wzb) {
    int i = blockIdx.x * 256 + threadIdx.x;
    if (i < O3 * CCH) {
        int o = i >> 9, c = i & 511;
        float v = (o < 256) ? tw[o * 512 + c] : (o < 512) ? pw[(o - 256) * 512 + c]
                                              : gw[(o - 512) * 512 + c];
        W3b[i] = f2h(v);
    } else {
        int j = i - O3 * CCH;
        if (j < CCH * CI) wzb[j] = f2h(wzw[j]);
    }
    if (i < O3) b3[i] = (i < 256) ? tb[i] : (i < 512) ? pb[i - 256] : gb[i - 512];
}

// ---------------------------------------------------------------------------
// transpose x[b][c][n] fp32 -> xt[b][n][c] fp16   (tile 64c x 128n)
__global__ __launch_bounds__(256) void transpose_x(const float* __restrict__ x,
                                                   u16* __restrict__ xt) {
    __shared__ float tile[64][129];
    int b = blockIdx.z;
    int n0 = blockIdx.x * 128, c0 = blockIdx.y * 64;
    const float* xb = x + ((size_t)b * CCH + c0) * NS + n0;
    int t = threadIdx.x;
    #pragma unroll
    for (int i = 0; i < 32; ++i) {
        int idx = t + i * 256;
        int c = idx >> 7, n = idx & 127;
        tile[c][n] = xb[(size_t)c * NS + n];
    }
    __syncthreads();
    u16* xo = xt + ((size_t)b * NS + n0) * CCH + c0;
    #pragma unroll
    for (int i = 0; i < 16; ++i) {
        int idx = t + i * 256;
        int cp = idx & 31, n = idx >> 5;
        unsigned lo = f2h(tile[2 * cp][n]);
        unsigned hi = f2h(tile[2 * cp + 1][n]);
        *(unsigned*)(xo + (size_t)n * CCH + 2 * cp) = lo | (hi << 16);
    }
}

// ---------------------------------------------------------------------------
// NT GEMM (fp16, MFMA): C[M][N] = A[M][K] * B[N][K]^T (+bias), C fp16
// 128x128 tile, BK=64, 256 threads (2x2 waves), m97-style global_load_lds.
// BIAS_MODE: 0 none, 1 by-row (fp32), 2 by-col (fp32)
template<int BIAS_MODE>
__global__ __launch_bounds__(256) void gemm_nt_f16(
        const u16* __restrict__ A, const u16* __restrict__ Bm,
        u16* __restrict__ C, const float* __restrict__ bias,
        int lda, int ldb, int ldc, int Ksize,
        size_t strideA, size_t strideB, size_t strideC) {
    __shared__ u16 As[128 * 64];
    __shared__ u16 Bs[128 * 64];
    const int t = threadIdx.x;
    const int l = t & 63, w = t >> 6;
    const int wr = w >> 1, wc = w & 1;
    const int fr = l & 15, fq = l >> 4;
    const int bz = blockIdx.z;
    const u16* gA = A + (size_t)bz * strideA + (size_t)(blockIdx.y * 128) * lda;
    const u16* gB = Bm + (size_t)bz * strideB + (size_t)(blockIdx.x * 128) * ldb;

    f32x4 acc[4][4];
    #pragma unroll
    for (int m = 0; m < 4; ++m)
        #pragma unroll
        for (int n = 0; n < 4; ++n) acc[m][n] = (f32x4)0.f;

    for (int k0 = 0; k0 < Ksize; k0 += 64) {
        #pragma unroll
        for (int i = 0; i < 4; ++i) {
            int cd = t + i * 256;                    // 16B chunk id, 0..1023
            int row = cd >> 3, k8 = (cd & 7) * 8;
            int lbase = (cd & ~63) * 8;              // wave-uniform LDS elem base
            gld16(&As[lbase], gA + (size_t)row * lda + k0 + k8);
            gld16(&Bs[lbase], gB + (size_t)row * ldb + k0 + k8);
        }
        __syncthreads();   // drains vmcnt -> LDS tiles ready

        half8 fa[4][2], fb[4][2];
        #pragma unroll
        for (int m = 0; m < 4; ++m)
            #pragma unroll
            for (int kk = 0; kk < 2; ++kk) {
                fa[m][kk] = *(const half8*)&As[(wr * 64 + m * 16 + fr) * 64 + kk * 32 + fq * 8];
                fb[m][kk] = *(const half8*)&Bs[(wc * 64 + m * 16 + fr) * 64 + kk * 32 + fq * 8];
            }
        #pragma unroll
        for (int kk = 0; kk < 2; ++kk)
            #pragma unroll
            for (int m = 0; m < 4; ++m)
                #pragma unroll
                for (int n = 0; n < 4; ++n)
                    acc[m][n] = __builtin_amdgcn_mfma_f32_16x16x32_f16(
                        fa[m][kk], fb[n][kk], acc[m][n], 0, 0, 0);
        __syncthreads();   // safe to overwrite LDS
    }

    u16* gC = C + (size_t)bz * strideC;
    const int crow0 = blockIdx.y * 128 + wr * 64;
    const int ccol0 = blockIdx.x * 128 + wc * 64;
    #pragma unroll
    for (int m = 0; m < 4; ++m) {
        #pragma unroll
        for (int n = 0; n < 4; ++n) {
            int col = ccol0 + n * 16 + fr;
            float cb = (BIAS_MODE == 2) ? bias[col] : 0.f;
            #pragma unroll
            for (int j = 0; j < 4; ++j) {
                int row = crow0 + m * 16 + fq * 4 + j;
                float v = acc[m][n][j] + cb;
                if (BIAS_MODE == 1) v += bias[row];
                gC[(size_t)row * ldc + col] = f2h(v);
            }
        }
    }
}

// ---------------------------------------------------------------------------
// maxpool 2x2x2 from proj_t[b][n][768]: phi cols 256..511 -> kb[b][m][ci],
//                                       g   cols 512..767 -> vg[b][ci][m]
__global__ __launch_bounds__(256) void pool_kernel(const u16* __restrict__ proj,
                                                   u16* __restrict__ kb, u16* __restrict__ vg) {
    int tid = blockIdx.x * 256 + threadIdx.x;
    int b = tid >> 18;
    int m = (tid >> 8) & 1023;
    int ci = tid & 255;
    int tp = m >> 8, hp = (m >> 4) & 15, wp = m & 15;
    const u16* pb = proj + (size_t)b * NS * O3;
    float mk = -1e30f, mv = -1e30f;
    #pragma unroll
    for (int d = 0; d < 8; ++d) {
        int dt = d >> 2, dh = (d >> 1) & 1, dw = d & 1;
        int n = (2 * tp + dt) * 1024 + (2 * hp + dh) * 32 + (2 * wp + dw);
        const u16* r = pb + (size_t)n * O3;
        mk = fmaxf(mk, h2f(r[256 + ci]));
        mv = fmaxf(mv, h2f(r[512 + ci]));
    }
    kb[((size_t)b * MS + m) * CI + ci] = f2h(mk);
    vg[((size_t)b * CI + ci) * MS + m] = f2h(mv);
}

// ---------------------------------------------------------------------------
// row softmax over S[row][1024] fp16, in place, normalized. 1 wave per row.
__global__ __launch_bounds__(256) void softmax_kernel(u16* __restrict__ S) {
    int w = threadIdx.x >> 6, l = threadIdx.x & 63;
    size_t row = (size_t)blockIdx.x * 4 + w;
    u16* p = S + row * MS;
    uint4 v[2];
    v[0] = *(const uint4*)(p + l * 8);
    v[1] = *(const uint4*)(p + 512 + l * 8);
    float f[16];
    #pragma unroll
    for (int r = 0; r < 2; ++r) {
        const u16* u = (const u16*)&v[r];
        #pragma unroll
        for (int j = 0; j < 8; ++j) f[r * 8 + j] = h2f(u[j]);
    }
    float mx = -1e30f;
    #pragma unroll
    for (int i = 0; i < 16; ++i) mx = fmaxf(mx, f[i]);
    #pragma unroll
    for (int off = 32; off; off >>= 1) mx = fmaxf(mx, __shfl_xor(mx, off));
    float s = 0.f;
    #pragma unroll
    for (int i = 0; i < 16; ++i) { float e = __expf(f[i] - mx); f[i] = e; s += e; }
    #pragma unroll
    for (int off = 32; off; off >>= 1) s += __shfl_xor(s, off);
    float inv = 1.f / s;
    #pragma unroll
    for (int r = 0; r < 2; ++r) {
        u16* u = (u16*)&v[r];
        #pragma unroll
        for (int j = 0; j < 8; ++j) u[j] = f2h(f[r * 8 + j] * inv);
    }
    *(uint4*)(p + l * 8) = v[0];
    *(uint4*)(p + 512 + l * 8) = v[1];
}

// ---------------------------------------------------------------------------
// BN stats over z[b][c][n] fp16: one block per channel
__global__ __launch_bounds__(256) void bn_stats(const u16* __restrict__ z,
                                                float* __restrict__ stats) {
    int c = blockIdx.x, t = threadIdx.x;
    float s = 0.f, q = 0.f;
    for (int b = 0; b < 8; ++b) {
        const u16* p = z + ((size_t)b * CCH + c) * NS;
        #pragma unroll
        for (int i = 0; i < 4; ++i) {
            uint4 v = *(const uint4*)(p + (t + i * 256) * 8);
            const u16* u = (const u16*)&v;
            #pragma unroll
            for (int j = 0; j < 8; ++j) { float f = h2f(u[j]); s += f; q += f * f; }
        }
    }
    #pragma unroll
    for (int off = 32; off; off >>= 1) { s += __shfl_xor(s, off); q += __shfl_xor(q, off); }
    __shared__ float rs[4], rq[4];
    int w = t >> 6;
    if ((t & 63) == 0) { rs[w] = s; rq[w] = q; }
    __syncthreads();
    if (t == 0) {
        float S2 = rs[0] + rs[1] + rs[2] + rs[3];
        float Q = rq[0] + rq[1] + rq[2] + rq[3];
        const float inv = 1.f / 65536.f;
        float mean = S2 * inv;
        float var = Q * inv - mean * mean;
        stats[c] = mean;
        stats[CCH + c] = rsqrtf(var + 1e-5f);
    }
}

// ---------------------------------------------------------------------------
// out = (z - mean)*rstd*gamma + beta + x   (8 elems/thread)
__global__ __launch_bounds__(256) void bn_final(const u16* __restrict__ z,
                                                const float* __restrict__ x,
                                                const float* __restrict__ stats,
                                                const float* __restrict__ gamma,
                                                const float* __restrict__ beta,
                                                float* __restrict__ out) {
    size_t i = ((size_t)blockIdx.x * 256 + threadIdx.x) * 8;
    int c = (int)((i >> 13) & 511);
    float g = gamma[c] * stats[CCH + c];
    float sh = beta[c] - stats[c] * g;
    uint4 zv = *(const uint4*)(z + i);
    const u16* u = (const u16*)&zv;
    float4 x0 = *(const float4*)(x + i);
    float4 x1 = *(const float4*)(x + i + 4);
    float4 o0, o1;
    o0.x = h2f(u[0]) * g + sh + x0.x;
    o0.y = h2f(u[1]) * g + sh + x0.y;
    o0.z = h2f(u[2]) * g + sh + x0.z;
    o0.w = h2f(u[3]) * g + sh + x0.w;
    o1.x = h2f(u[4]) * g + sh + x1.x;
    o1.y = h2f(u[5]) * g + sh + x1.y;
    o1.z = h2f(u[6]) * g + sh + x1.z;
    o1.w = h2f(u[7]) * g + sh + x1.w;
    *(float4*)(out + i) = o0;
    *(float4*)(out + i + 4) = o1;
}

// ---------------------------------------------------------------------------
extern "C" void kernel_launch(void* const* d_in, const int* in_sizes, int n_in,
                              void* d_out, int out_size, void* d_ws, size_t ws_size,
                              hipStream_t stream) {
    const float* x       = (const float*)d_in[0];
    const float* theta_w = (const float*)d_in[1];
    const float* theta_b = (const float*)d_in[2];
    const float* phi_w   = (const float*)d_in[3];
    const float* phi_b   = (const float*)d_in[4];
    const float* g_w     = (const float*)d_in[5];
    const float* g_b     = (const float*)d_in[6];
    const float* wz_w    = (const float*)d_in[7];
    const float* wz_b    = (const float*)d_in[8];
    const float* gamma   = (const float*)d_in[9];
    const float* beta    = (const float*)d_in[10];

    char* base = (char*)d_ws;
    u16*   W3b  = (u16*)base;                              // 786432 B
    float* b3   = (float*)(base + 786432);                 // 3072 B
    u16*   wzb  = (u16*)(base + 789504);                   // 262144 B
    float* stats= (float*)(base + 1051648);                // 4096 B
    // region X (67.1 MB): xt, then kb+vg, then z
    u16* xt   = (u16*)(base + 1056768);
    u16* kb   = xt;                                        // after xt dead
    u16* vg   = xt + (size_t)8 * MS * CI;                  // +4 MB
    u16* z    = xt;                                        // after kb/vg dead
    // region P (100.7 MB): proj_t, then y
    u16* proj = (u16*)(base + 1056768 + 67108864);
    u16* y    = proj;                                      // after proj dead
    // region S (134.2 MB)
    u16* S    = (u16*)(base + 1056768 + 67108864 + 100663296);

    // 1) weights
    prep_w<<<2048, 256, 0, stream>>>(theta_w, theta_b, phi_w, phi_b, g_w, g_b,
                                     wz_w, W3b, b3, wzb);
    // 2) x -> xt (fp16, [b][n][c])
    transpose_x<<<dim3(64, 8, 8), 256, 0, stream>>>(x, xt);

    // 3) proj_t[b][n][768] = xt * W3b^T + b3(col)
    gemm_nt_f16<2><<<dim3(6, 64, 8), 256, 0, stream>>>(
        xt, W3b, proj, b3, CCH, CCH, O3, CCH,
        (size_t)NS * CCH, 0, (size_t)NS * O3);

    // 4) pool -> kb[b][m][ci], vg[b][ci][m]
    pool_kernel<<<8192, 256, 0, stream>>>(proj, kb, vg);

    // 5) S[b][n][m] = theta(proj_t cols 0..255) * kb^T
    gemm_nt_f16<0><<<dim3(8, 64, 8), 256, 0, stream>>>(
        proj, kb, S, nullptr, O3, CI, MS, CI,
        (size_t)NS * O3, (size_t)MS * CI, (size_t)NS * MS);

    // 6) softmax rows (in place, normalized)
    softmax_kernel<<<16384, 256, 0, stream>>>(S);

    // 7) y[b][n][ci] = P * vg^T
    gemm_nt_f16<0><<<dim3(2, 64, 8), 256, 0, stream>>>(
        S, vg, y, nullptr, MS, MS, CI, MS,
        (size_t)NS * MS, (size_t)CI * MS, (size_t)NS * CI);

    // 8) z[b][c][n] = wzb * y^T + wz_b(row)
    gemm_nt_f16<1><<<dim3(64, 4, 8), 256, 0, stream>>>(
        wzb, y, z, wz_b, CI, CI, NS, CI,
        0, (size_t)NS * CI, (size_t)CCH * NS);

    // 9) BN stats
    bn_stats<<<CCH, 256, 0, stream>>>(z, stats);

    // 10) normalize + residual
    bn_final<<<16384, 256, 0, stream>>>(z, x, stats, gamma, beta, (float*)d_out);
}

// Round 4
// 426.782 us; speedup vs baseline: 5.8044x; 1.0296x over previous
//
#include <hip/hip_runtime.h>
#include <math.h>

typedef unsigned short u16;
typedef __attribute__((ext_vector_type(8))) _Float16 half8;
typedef __attribute__((ext_vector_type(4))) float f32x4;

#define NS 8192
#define MS 1024
#define CCH 512
#define CI 256
#define O3 768

// ---- fp16 helpers (bit-level storage as u16) ----
__device__ __forceinline__ float h2f(u16 u) {
    _Float16 h; *(u16*)&h = u; return (float)h;
}
__device__ __forceinline__ u16 f2h(float f) {
    _Float16 h = (_Float16)f; return *(u16*)&h;
}

// async global->LDS 16B
__device__ __forceinline__ void gld16(u16* lds, const u16* g) {
    __builtin_amdgcn_global_load_lds((const __attribute__((address_space(1))) void*)g,
                                     (__attribute__((address_space(3))) void*)lds,
                                     16, 0, 0);
}

// ---------------------------------------------------------------------------
// prep: concat+convert weights to fp16
__global__ void prep_w(const float* __restrict__ tw, const float* __restrict__ tb,
                       const float* __restrict__ pw, const float* __restrict__ pb,
                       const float* __restrict__ gw, const float* __restrict__ gb,
                       const float* __restrict__ wzw,
                       u16* __restrict__ W3b, float* __restrict__ b3, u16* __restrict__ wzb) {
    int i = blockIdx.x * 256 + threadIdx.x;
    if (i < O3 * CCH) {
        int o = i >> 9, c = i & 511;
        float v = (o < 256) ? tw[o * 512 + c] : (o < 512) ? pw[(o - 256) * 512 + c]
                                              : gw[(o - 512) * 512 + c];
        W3b[i] = f2h(v);
    } else {
        int j = i - O3 * CCH;
        if (j < CCH * CI) wzb[j] = f2h(wzw[j]);
    }
    if (i < O3) b3[i] = (i < 256) ? tb[i] : (i < 512) ? pb[i - 256] : gb[i - 512];
}

// ---------------------------------------------------------------------------
// transpose x[b][c][n] fp32 -> xt[b][n][c] fp16   (tile 64c x 128n)
__global__ __launch_bounds__(256) void transpose_x(const float* __restrict__ x,
                                                   u16* __restrict__ xt) {
    __shared__ float tile[64][129];
    int b = blockIdx.z;
    int n0 = blockIdx.x * 128, c0 = blockIdx.y * 64;
    const float* xb = x + ((size_t)b * CCH + c0) * NS + n0;
    int t = threadIdx.x;
    #pragma unroll
    for (int i = 0; i < 32; ++i) {
        int idx = t + i * 256;
        int c = idx >> 7, n = idx & 127;
        tile[c][n] = xb[(size_t)c * NS + n];
    }
    __syncthreads();
    u16* xo = xt + ((size_t)b * NS + n0) * CCH + c0;
    #pragma unroll
    for (int i = 0; i < 16; ++i) {
        int idx = t + i * 256;
        int cp = idx & 31, n = idx >> 5;
        unsigned lo = f2h(tile[2 * cp][n]);
        unsigned hi = f2h(tile[2 * cp + 1][n]);
        *(unsigned*)(xo + (size_t)n * CCH + 2 * cp) = lo | (hi << 16);
    }
}

// ---------------------------------------------------------------------------
// NT GEMM (fp16, MFMA): C[M][N] = A[M][K] * B[N][K]^T (+bias), C fp16
// BIAS_MODE: 0 none, 1 by-row (fp32), 2 by-col (fp32)
template<int BIAS_MODE>
__global__ __launch_bounds__(256) void gemm_nt_f16(
        const u16* __restrict__ A, const u16* __restrict__ Bm,
        u16* __restrict__ C, const float* __restrict__ bias,
        int lda, int ldb, int ldc, int Ksize,
        size_t strideA, size_t strideB, size_t strideC) {
    __shared__ u16 As[128 * 64];
    __shared__ u16 Bs[128 * 64];
    const int t = threadIdx.x;
    const int l = t & 63, w = t >> 6;
    const int wr = w >> 1, wc = w & 1;
    const int fr = l & 15, fq = l >> 4;
    const int bz = blockIdx.z;
    const u16* gA = A + (size_t)bz * strideA + (size_t)(blockIdx.y * 128) * lda;
    const u16* gB = Bm + (size_t)bz * strideB + (size_t)(blockIdx.x * 128) * ldb;

    f32x4 acc[4][4];
    #pragma unroll
    for (int m = 0; m < 4; ++m)
        #pragma unroll
        for (int n = 0; n < 4; ++n) acc[m][n] = (f32x4)0.f;

    for (int k0 = 0; k0 < Ksize; k0 += 64) {
        #pragma unroll
        for (int i = 0; i < 4; ++i) {
            int cd = t + i * 256;
            int row = cd >> 3, k8 = (cd & 7) * 8;
            int lbase = (cd & ~63) * 8;
            gld16(&As[lbase], gA + (size_t)row * lda + k0 + k8);
            gld16(&Bs[lbase], gB + (size_t)row * ldb + k0 + k8);
        }
        __syncthreads();

        half8 fa[4][2], fb[4][2];
        #pragma unroll
        for (int m = 0; m < 4; ++m)
            #pragma unroll
            for (int kk = 0; kk < 2; ++kk) {
                fa[m][kk] = *(const half8*)&As[(wr * 64 + m * 16 + fr) * 64 + kk * 32 + fq * 8];
                fb[m][kk] = *(const half8*)&Bs[(wc * 64 + m * 16 + fr) * 64 + kk * 32 + fq * 8];
            }
        #pragma unroll
        for (int kk = 0; kk < 2; ++kk)
            #pragma unroll
            for (int m = 0; m < 4; ++m)
                #pragma unroll
                for (int n = 0; n < 4; ++n)
                    acc[m][n] = __builtin_amdgcn_mfma_f32_16x16x32_f16(
                        fa[m][kk], fb[n][kk], acc[m][n], 0, 0, 0);
        __syncthreads();
    }

    u16* gC = C + (size_t)bz * strideC;
    const int crow0 = blockIdx.y * 128 + wr * 64;
    const int ccol0 = blockIdx.x * 128 + wc * 64;
    #pragma unroll
    for (int m = 0; m < 4; ++m) {
        #pragma unroll
        for (int n = 0; n < 4; ++n) {
            int col = ccol0 + n * 16 + fr;
            float cb = (BIAS_MODE == 2) ? bias[col] : 0.f;
            #pragma unroll
            for (int j = 0; j < 4; ++j) {
                int row = crow0 + m * 16 + fq * 4 + j;
                float v = acc[m][n][j] + cb;
                if (BIAS_MODE == 1) v += bias[row];
                gC[(size_t)row * ldc + col] = f2h(v);
            }
        }
    }
}

// ---------------------------------------------------------------------------
// maxpool 2x2x2 from proj_t[b][n][768]: phi cols 256..511 -> kb[b][m][ci],
//                                       g   cols 512..767 -> vg[b][ci][m]
__global__ __launch_bounds__(256) void pool_kernel(const u16* __restrict__ proj,
                                                   u16* __restrict__ kb, u16* __restrict__ vg) {
    int tid = blockIdx.x * 256 + threadIdx.x;
    int b = tid >> 18;
    int m = (tid >> 8) & 1023;
    int ci = tid & 255;
    int tp = m >> 8, hp = (m >> 4) & 15, wp = m & 15;
    const u16* pb = proj + (size_t)b * NS * O3;
    float mk = -1e30f, mv = -1e30f;
    #pragma unroll
    for (int d = 0; d < 8; ++d) {
        int dt = d >> 2, dh = (d >> 1) & 1, dw = d & 1;
        int n = (2 * tp + dt) * 1024 + (2 * hp + dh) * 32 + (2 * wp + dw);
        const u16* r = pb + (size_t)n * O3;
        mk = fmaxf(mk, h2f(r[256 + ci]));
        mv = fmaxf(mv, h2f(r[512 + ci]));
    }
    kb[((size_t)b * MS + m) * CI + ci] = f2h(mk);
    vg[((size_t)b * CI + ci) * MS + m] = f2h(mv);
}

// ---------------------------------------------------------------------------
// Fused flash attention: Q = proj[b][n][0:256] (stride 768), K = kb[b][m][ci],
// V^T = vg[b][ci][m].  y[b][n][ci] = softmax(QK^T) V.
// Block: 128 q-rows, 4 waves row-stacked (32 rows each). m-tiles of 64,
// K/V double-buffered LDS with XOR-swizzle (pre-swizzled gld16 source).
__global__ __launch_bounds__(256) void attn_fused(
        const u16* __restrict__ proj, const u16* __restrict__ kb,
        const u16* __restrict__ vg, u16* __restrict__ y) {
    __shared__ u16 Ks[2][64 * 256];     // 2 x 32 KB
    __shared__ u16 Vs[2][256 * 64];     // 2 x 32 KB
    __shared__ u16 Ps[128][72];         // 18 KB, stride 144B (16B-aligned, 2-way free)

    const int b = blockIdx.y;
    const int n0 = blockIdx.x * 128;
    const int t = threadIdx.x;
    const int l = t & 63, w = t >> 6;
    const int fr = l & 15, fq = l >> 4;

    const u16* projb = proj + (size_t)b * NS * O3;
    const u16* kbb = kb + (size_t)b * MS * CI;
    const u16* vgb = vg + (size_t)b * CI * MS;

    // Q fragments in registers: rows n0 + w*32 + mf*16 + fr, k = kk*32 + fq*8
    half8 qf[2][8];
    #pragma unroll
    for (int mf = 0; mf < 2; ++mf) {
        const u16* qrow = projb + (size_t)(n0 + w * 32 + mf * 16 + fr) * O3 + fq * 8;
        #pragma unroll
        for (int kk = 0; kk < 8; ++kk)
            qf[mf][kk] = *(const half8*)(qrow + kk * 32);
    }

    f32x4 accO[2][16];
    #pragma unroll
    for (int mf = 0; mf < 2; ++mf)
        #pragma unroll
        for (int nf = 0; nf < 16; ++nf) accO[mf][nf] = (f32x4)0.f;
    float m_run[2][4], l_run[2][4];
    #pragma unroll
    for (int mf = 0; mf < 2; ++mf)
        #pragma unroll
        for (int j = 0; j < 4; ++j) { m_run[mf][j] = -1e30f; l_run[mf][j] = 0.f; }

    // stage K/V tile for m0 into buffer `buf` (pre-swizzled source, linear dest)
    #define STAGE_KV(buf, m0)                                                     \
        {                                                                         \
            _Pragma("unroll")                                                     \
            for (int i = 0; i < 8; ++i) {                                         \
                int c = t + i * 256;                                              \
                int lb = (c & ~63) << 3;                                          \
                int krow = c >> 5, kk8 = c & 31;                                  \
                gld16(&Ks[buf][lb],                                               \
                      kbb + (size_t)((m0) + krow) * CI + ((kk8 ^ (krow & 7)) << 3)); \
                int vrow = c >> 3, vk8 = c & 7;                                   \
                gld16(&Vs[buf][lb],                                               \
                      vgb + (size_t)vrow * MS + (m0) + ((vk8 ^ (vrow & 7)) << 3)); \
            }                                                                     \
        }

    STAGE_KV(0, 0);
    __syncthreads();

    for (int mt = 0; mt < 16; ++mt) {
        const int cur = mt & 1;
        if (mt < 15) STAGE_KV(cur ^ 1, (mt + 1) * 64);

        // ---- QK^T: S-tile 32 q-rows x 64 m-cols per wave ----
        f32x4 accS[2][4];
        #pragma unroll
        for (int mf = 0; mf < 2; ++mf)
            #pragma unroll
            for (int nf = 0; nf < 4; ++nf) accS[mf][nf] = (f32x4)0.f;
        #pragma unroll
        for (int kk = 0; kk < 8; ++kk) {
            half8 fb[4];
            #pragma unroll
            for (int nf = 0; nf < 4; ++nf) {
                int row = nf * 16 + fr;
                fb[nf] = *(const half8*)&Ks[cur][row * 256 + (((kk << 2) | fq) ^ (row & 7)) * 8];
            }
            #pragma unroll
            for (int mf = 0; mf < 2; ++mf)
                #pragma unroll
                for (int nf = 0; nf < 4; ++nf)
                    accS[mf][nf] = __builtin_amdgcn_mfma_f32_16x16x32_f16(
                        qf[mf][kk], fb[nf], accS[mf][nf], 0, 0, 0);
        }

        // ---- online softmax (rows fully in-wave) ----
        float pm[2][4];
        #pragma unroll
        for (int mf = 0; mf < 2; ++mf)
            #pragma unroll
            for (int j = 0; j < 4; ++j)
                pm[mf][j] = fmaxf(fmaxf(accS[mf][0][j], accS[mf][1][j]),
                                  fmaxf(accS[mf][2][j], accS[mf][3][j]));
        #pragma unroll
        for (int off = 1; off < 16; off <<= 1)
            #pragma unroll
            for (int mf = 0; mf < 2; ++mf)
                #pragma unroll
                for (int j = 0; j < 4; ++j)
                    pm[mf][j] = fmaxf(pm[mf][j], __shfl_xor(pm[mf][j], off));

        int chg = 0;
        #pragma unroll
        for (int mf = 0; mf < 2; ++mf)
            #pragma unroll
            for (int j = 0; j < 4; ++j) chg |= (pm[mf][j] > m_run[mf][j]);
        if (__any(chg)) {   // exact defer: skip when max unchanged everywhere
            #pragma unroll
            for (int mf = 0; mf < 2; ++mf)
                #pragma unroll
                for (int j = 0; j < 4; ++j) {
                    float mn = fmaxf(m_run[mf][j], pm[mf][j]);
                    float a = __expf(m_run[mf][j] - mn);
                    m_run[mf][j] = mn;
                    l_run[mf][j] *= a;
                    #pragma unroll
                    for (int nf = 0; nf < 16; ++nf) accO[mf][nf][j] *= a;
                }
        }

        // P = exp(S - m), row sums, store P to LDS (own band only)
        #pragma unroll
        for (int mf = 0; mf < 2; ++mf)
            #pragma unroll
            for (int j = 0; j < 4; ++j) {
                float ps = 0.f;
                #pragma unroll
                for (int nf = 0; nf < 4; ++nf) {
                    float p = __expf(accS[mf][nf][j] - m_run[mf][j]);
                    ps += p;
                    Ps[w * 32 + mf * 16 + fq * 4 + j][nf * 16 + fr] = f2h(p);
                }
                #pragma unroll
                for (int off = 1; off < 16; off <<= 1) ps += __shfl_xor(ps, off);
                l_run[mf][j] += ps;
            }

        // ---- PV: O += P * V (A from Ps own band, B from Vs swizzled) ----
        #pragma unroll
        for (int kkm = 0; kkm < 2; ++kkm) {
            half8 fa[2];
            #pragma unroll
            for (int mf = 0; mf < 2; ++mf)
                fa[mf] = *(const half8*)&Ps[w * 32 + mf * 16 + fr][kkm * 32 + fq * 8];
            #pragma unroll
            for (int nf = 0; nf < 16; ++nf) {
                int row = nf * 16 + fr;
                half8 fbv = *(const half8*)&Vs[cur][row * 64 + (((kkm << 2) | fq) ^ (row & 7)) * 8];
                #pragma unroll
                for (int mf = 0; mf < 2; ++mf)
                    accO[mf][nf] = __builtin_amdgcn_mfma_f32_16x16x32_f16(
                        fa[mf], fbv, accO[mf][nf], 0, 0, 0);
            }
        }
        __syncthreads();
    }

    // epilogue: y[n][ci] = O / l
    u16* yb = y + ((size_t)b * NS + n0 + w * 32) * CI;
    #pragma unroll
    for (int mf = 0; mf < 2; ++mf)
        #pragma unroll
        for (int j = 0; j < 4; ++j) {
            float inv = 1.f / l_run[mf][j];
            int row = mf * 16 + fq * 4 + j;
            #pragma unroll
            for (int nf = 0; nf < 16; ++nf)
                yb[(size_t)row * CI + nf * 16 + fr] = f2h(accO[mf][nf][j] * inv);
        }
    #undef STAGE_KV
}

// ---------------------------------------------------------------------------
// BN stats over z[b][c][n] fp16: one block per channel
__global__ __launch_bounds__(256) void bn_stats(const u16* __restrict__ z,
                                                float* __restrict__ stats) {
    int c = blockIdx.x, t = threadIdx.x;
    float s = 0.f, q = 0.f;
    for (int b = 0; b < 8; ++b) {
        const u16* p = z + ((size_t)b * CCH + c) * NS;
        #pragma unroll
        for (int i = 0; i < 4; ++i) {
            uint4 v = *(const uint4*)(p + (t + i * 256) * 8);
            const u16* u = (const u16*)&v;
            #pragma unroll
            for (int j = 0; j < 8; ++j) { float f = h2f(u[j]); s += f; q += f * f; }
        }
    }
    #pragma unroll
    for (int off = 32; off; off >>= 1) { s += __shfl_xor(s, off); q += __shfl_xor(q, off); }
    __shared__ float rs[4], rq[4];
    int w = t >> 6;
    if ((t & 63) == 0) { rs[w] = s; rq[w] = q; }
    __syncthreads();
    if (t == 0) {
        float S2 = rs[0] + rs[1] + rs[2] + rs[3];
        float Q = rq[0] + rq[1] + rq[2] + rq[3];
        const float inv = 1.f / 65536.f;
        float mean = S2 * inv;
        float var = Q * inv - mean * mean;
        stats[c] = mean;
        stats[CCH + c] = rsqrtf(var + 1e-5f);
    }
}

// ---------------------------------------------------------------------------
// out = (z - mean)*rstd*gamma + beta + x   (8 elems/thread)
__global__ __launch_bounds__(256) void bn_final(const u16* __restrict__ z,
                                                const float* __restrict__ x,
                                                const float* __restrict__ stats,
                                                const float* __restrict__ gamma,
                                                const float* __restrict__ beta,
                                                float* __restrict__ out) {
    size_t i = ((size_t)blockIdx.x * 256 + threadIdx.x) * 8;
    int c = (int)((i >> 13) & 511);
    float g = gamma[c] * stats[CCH + c];
    float sh = beta[c] - stats[c] * g;
    uint4 zv = *(const uint4*)(z + i);
    const u16* u = (const u16*)&zv;
    float4 x0 = *(const float4*)(x + i);
    float4 x1 = *(const float4*)(x + i + 4);
    float4 o0, o1;
    o0.x = h2f(u[0]) * g + sh + x0.x;
    o0.y = h2f(u[1]) * g + sh + x0.y;
    o0.z = h2f(u[2]) * g + sh + x0.z;
    o0.w = h2f(u[3]) * g + sh + x0.w;
    o1.x = h2f(u[4]) * g + sh + x1.x;
    o1.y = h2f(u[5]) * g + sh + x1.y;
    o1.z = h2f(u[6]) * g + sh + x1.z;
    o1.w = h2f(u[7]) * g + sh + x1.w;
    *(float4*)(out + i) = o0;
    *(float4*)(out + i + 4) = o1;
}

// ---------------------------------------------------------------------------
extern "C" void kernel_launch(void* const* d_in, const int* in_sizes, int n_in,
                              void* d_out, int out_size, void* d_ws, size_t ws_size,
                              hipStream_t stream) {
    const float* x       = (const float*)d_in[0];
    const float* theta_w = (const float*)d_in[1];
    const float* theta_b = (const float*)d_in[2];
    const float* phi_w   = (const float*)d_in[3];
    const float* phi_b   = (const float*)d_in[4];
    const float* g_w     = (const float*)d_in[5];
    const float* g_b     = (const float*)d_in[6];
    const float* wz_w    = (const float*)d_in[7];
    const float* wz_b    = (const float*)d_in[8];
    const float* gamma   = (const float*)d_in[9];
    const float* beta    = (const float*)d_in[10];

    char* base = (char*)d_ws;
    u16*   W3b  = (u16*)base;                              // 786432 B
    float* b3   = (float*)(base + 786432);                 // 3072 B
    u16*   wzb  = (u16*)(base + 789504);                   // 262144 B
    float* stats= (float*)(base + 1051648);                // 4096 B
    // region X (67.1 MB): xt, then kb+vg, then z
    u16* xt   = (u16*)(base + 1056768);
    u16* kb   = xt;                                        // after xt dead
    u16* vg   = xt + (size_t)8 * MS * CI;                  // +4 MB
    u16* z    = xt;                                        // after kb/vg dead
    // region P (100.7 MB): proj_t
    u16* proj = (u16*)(base + 1056768 + 67108864);
    // region Y (33.6 MB): y  (must NOT alias proj: attn reads Q from proj)
    u16* y    = (u16*)(base + 1056768 + 67108864 + 100663296);

    // 1) weights
    prep_w<<<2048, 256, 0, stream>>>(theta_w, theta_b, phi_w, phi_b, g_w, g_b,
                                     wz_w, W3b, b3, wzb);
    // 2) x -> xt (fp16, [b][n][c])
    transpose_x<<<dim3(64, 8, 8), 256, 0, stream>>>(x, xt);

    // 3) proj_t[b][n][768] = xt * W3b^T + b3(col)
    gemm_nt_f16<2><<<dim3(6, 64, 8), 256, 0, stream>>>(
        xt, W3b, proj, b3, CCH, CCH, O3, CCH,
        (size_t)NS * CCH, 0, (size_t)NS * O3);

    // 4) pool -> kb[b][m][ci], vg[b][ci][m]
    pool_kernel<<<8192, 256, 0, stream>>>(proj, kb, vg);

    // 5) fused attention -> y[b][n][ci]
    attn_fused<<<dim3(64, 8), 256, 0, stream>>>(proj, kb, vg, y);

    // 6) z[b][c][n] = wzb * y^T + wz_b(row)
    gemm_nt_f16<1><<<dim3(64, 4, 8), 256, 0, stream>>>(
        wzb, y, z, wz_b, CI, CI, NS, CI,
        0, (size_t)NS * CI, (size_t)CCH * NS);

    // 7) BN stats
    bn_stats<<<CCH, 256, 0, stream>>>(z, stats);

    // 8) normalize + residual
    bn_final<<<16384, 256, 0, stream>>>(z, x, stats, gamma, beta, (float*)d_out);
}